// Round 1
// baseline (132.446 us; speedup 1.0000x reference)
//
#include <hip/hip_runtime.h>
#include <math.h>

#define D_DIM 512
#define H_DIM 256
#define E_NUM 10
#define RPB   256              // rows per block
#define CHUNK 16               // d-elements per staged chunk
#define NCHUNK (D_DIM / CHUNK) // 32
#define ROWPAD 18              // dwords per LDS row (16 data + 2 pad)

// ---------- precompute: W_eff = (W_proj @ emb^T)/16 and bias_g ----------
__global__ __launch_bounds__(256) void pre_wg(const float* __restrict__ Wp,
                                              const float* __restrict__ bp,
                                              const float* __restrict__ emb,
                                              float* __restrict__ wg,
                                              float* __restrict__ bg) {
  int gid = blockIdx.x * 256 + threadIdx.x;
  if (gid < E_NUM * D_DIM) {
    int d = gid / E_NUM;
    int e = gid - d * E_NUM;
    const float* wr = Wp + (size_t)d * H_DIM;
    const float* er = emb + (size_t)e * H_DIM;
    float s0 = 0.f, s1 = 0.f, s2 = 0.f, s3 = 0.f;
#pragma unroll 4
    for (int h = 0; h < H_DIM; h += 4) {
      float4 a = *(const float4*)(wr + h);
      float4 b = *(const float4*)(er + h);
      s0 = fmaf(a.x, b.x, s0); s1 = fmaf(a.y, b.y, s1);
      s2 = fmaf(a.z, b.z, s2); s3 = fmaf(a.w, b.w, s3);
    }
    wg[(size_t)e * D_DIM + d] = ((s0 + s1) + (s2 + s3)) * 0.0625f;
  } else if (gid < E_NUM * D_DIM + E_NUM) {
    int e = gid - E_NUM * D_DIM;
    const float* er = emb + (size_t)e * H_DIM;
    float s = 0.f;
    for (int h = 0; h < H_DIM; ++h) s = fmaf(bp[h], er[h], s);
    bg[e] = s * 0.0625f;
  }
}

// ---------- precompute: normalized expert rows + trust*staleness ----------
__global__ __launch_bounds__(64) void pre_en(const float* __restrict__ ef,
                                             const float* __restrict__ trust,
                                             const float* __restrict__ dtv,
                                             float* __restrict__ en,
                                             float* __restrict__ cf) {
  int e = blockIdx.x, l = threadIdx.x;
  const float* row = ef + (size_t)e * D_DIM;
  float s = 0.f;
#pragma unroll
  for (int j = 0; j < D_DIM / 64; ++j) { float v = row[l + 64 * j]; s = fmaf(v, v, s); }
#pragma unroll
  for (int o = 32; o; o >>= 1) s += __shfl_xor(s, o, 64);
  float inv = 1.f / fmaxf(sqrtf(s), 1e-8f);
#pragma unroll
  for (int j = 0; j < D_DIM / 64; ++j)
    en[(size_t)e * D_DIM + l + 64 * j] = row[l + 64 * j] * inv;
  if (l == 0) cf[e] = trust[e] * expf(-0.001f * dtv[e]);
}

// ---------- main: one thread per row ----------
__global__ __launch_bounds__(256, 2) void router_main(
    const float* __restrict__ feat, const float* __restrict__ wg,
    const float* __restrict__ en, const float* __restrict__ cf,
    const float* __restrict__ bg, float* __restrict__ out, int B) {
  __shared__ float lds[2][RPB * ROWPAD];
  const int t = threadIdx.x;
  const size_t r0 = (size_t)blockIdx.x * RPB;
  const int rsub = t >> 2, qw = t & 3;
  const int wkey = (rsub >> 4) & 3;   // swizzle key of rows this thread stages
  const int sw = (t >> 4) & 3;        // swizzle key of this thread's own row
  const float* gsrc = feat + (r0 + rsub) * D_DIM + (qw << 2);

  float gacc[E_NUM], sacc[E_NUM], nrm = 0.f;
#pragma unroll
  for (int e = 0; e < E_NUM; ++e) { gacc[e] = 0.f; sacc[e] = 0.f; }

  float4 nA[4], nB[4];

  auto gload = [&](float4* v, int c) {
#pragma unroll
    for (int j = 0; j < 4; ++j)
      v[j] = *(const float4*)(gsrc + (size_t)(64 * j) * D_DIM + c * CHUNK);
  };
  auto swrite = [&](float* dst, const float4* v) {
    const int qx = (qw ^ wkey) << 2;
#pragma unroll
    for (int j = 0; j < 4; ++j) {
      float* p = dst + (rsub + 64 * j) * ROWPAD + qx;
      *(float2*)p       = make_float2(v[j].x, v[j].y);
      *(float2*)(p + 2) = make_float2(v[j].z, v[j].w);
    }
  };
  auto compute = [&](const float* buf, int c) {
#pragma unroll
    for (int q = 0; q < 4; ++q) {
      const float* fp = buf + t * ROWPAD + ((q ^ sw) << 2);
      float2 fa = *(const float2*)fp;
      float2 fb = *(const float2*)(fp + 2);
      const int db = c * CHUNK + (q << 2);
      const float* wp = wg + db;
#pragma unroll
      for (int e = 0; e < E_NUM; ++e) {
        float4 w = *(const float4*)(wp + (size_t)e * D_DIM);  // wave-uniform
        float a = gacc[e];
        a = fmaf(fa.x, w.x, a); a = fmaf(fa.y, w.y, a);
        a = fmaf(fb.x, w.z, a); a = fmaf(fb.y, w.w, a);
        gacc[e] = a;
      }
      const float* sp = en + db;
#pragma unroll
      for (int e = 0; e < E_NUM; ++e) {
        float4 w = *(const float4*)(sp + (size_t)e * D_DIM);  // wave-uniform
        float a = sacc[e];
        a = fmaf(fa.x, w.x, a); a = fmaf(fa.y, w.y, a);
        a = fmaf(fb.x, w.z, a); a = fmaf(fb.y, w.w, a);
        sacc[e] = a;
      }
      nrm = fmaf(fa.x, fa.x, nrm); nrm = fmaf(fa.y, fa.y, nrm);
      nrm = fmaf(fb.x, fb.x, nrm); nrm = fmaf(fb.y, fb.y, nrm);
    }
  };

  // prologue: chunk0 -> LDS0, prefetch chunk1, chunk2
  gload(nA, 0);
  swrite(lds[0], nA);
  gload(nA, 1);
  gload(nB, 2);
  __syncthreads();

#pragma unroll 1
  for (int c = 0; c < NCHUNK; c += 2) {
    swrite(lds[1], nA);                       // chunk c+1 -> buf1
    if (c + 3 < NCHUNK) gload(nA, c + 3);
    compute(lds[0], c);
    __syncthreads();
    if (c + 2 < NCHUNK) {
      swrite(lds[0], nB);                     // chunk c+2 -> buf0
      if (c + 4 < NCHUNK) gload(nB, c + 4);
    }
    compute(lds[1], c + 1);
    __syncthreads();
  }

  // ---------- epilogue ----------
  const float inv = 1.f / fmaxf(sqrtf(nrm), 1e-8f);
  float probs[E_NUM];
  float m = -1e30f;
#pragma unroll
  for (int e = 0; e < E_NUM; ++e) {
    float logit = gacc[e] + bg[e];
    float gate = 1.f / (1.f + __expf(-logit));
    float sim = fmaf(sacc[e] * inv, 0.5f, 0.5f);
    float sc = gate * cf[e] * sim;
    probs[e] = sc;
    m = fmaxf(m, sc);
  }
  float Z = 0.f;
#pragma unroll
  for (int e = 0; e < E_NUM; ++e) { float p = __expf(probs[e] - m); probs[e] = p; Z += p; }
  const float invZ = 1.f / Z;
#pragma unroll
  for (int e = 0; e < E_NUM; ++e) probs[e] *= invZ;

  // stable top-3 (strict >, lowest index wins ties) == jax.lax.top_k
  int i0 = 0; float b0 = probs[0];
#pragma unroll
  for (int e = 1; e < E_NUM; ++e) if (probs[e] > b0) { b0 = probs[e]; i0 = e; }
  int i1 = -1; float b1 = -1.f;
#pragma unroll
  for (int e = 0; e < E_NUM; ++e) if (e != i0 && probs[e] > b1) { b1 = probs[e]; i1 = e; }
  int i2 = -1; float b2 = -1.f;
#pragma unroll
  for (int e = 0; e < E_NUM; ++e) if (e != i0 && e != i1 && probs[e] > b2) { b2 = probs[e]; i2 = e; }

  const float wnorm = 1.f / (b0 + b1 + b2);
  const size_t r = r0 + t;
  float* ow = out + r * 3;
  ow[0] = b0 * wnorm; ow[1] = b1 * wnorm; ow[2] = b2 * wnorm;
  float* oi = out + (size_t)B * 3 + r * 3;
  oi[0] = (float)i0; oi[1] = (float)i1; oi[2] = (float)i2;
  float* op = out + (size_t)B * 6 + r * E_NUM;
#pragma unroll
  for (int e = 0; e < E_NUM; ++e) op[e] = probs[e];
}

extern "C" void kernel_launch(void* const* d_in, const int* in_sizes, int n_in,
                              void* d_out, int out_size, void* d_ws, size_t ws_size,
                              hipStream_t stream) {
  const float* feat  = (const float*)d_in[0];
  const float* Wp    = (const float*)d_in[1];
  const float* bp    = (const float*)d_in[2];
  const float* emb   = (const float*)d_in[3];
  const float* ef    = (const float*)d_in[4];
  const float* trust = (const float*)d_in[5];
  const float* dtv   = (const float*)d_in[6];
  float* out = (float*)d_out;

  float* wg = (float*)d_ws;            // E_NUM*D_DIM
  float* en = wg + E_NUM * D_DIM;      // E_NUM*D_DIM
  float* cf = en + E_NUM * D_DIM;      // E_NUM
  float* bg = cf + E_NUM;              // E_NUM

  const int B = in_sizes[0] / D_DIM;

  hipLaunchKernelGGL(pre_wg, dim3((E_NUM * D_DIM + E_NUM + 255) / 256), dim3(256),
                     0, stream, Wp, bp, emb, wg, bg);
  hipLaunchKernelGGL(pre_en, dim3(E_NUM), dim3(64), 0, stream, ef, trust, dtv, en, cf);
  hipLaunchKernelGGL(router_main, dim3(B / RPB), dim3(256), 0, stream,
                     feat, wg, en, cf, bg, out, B);
}

// Round 2
// 106.591 us; speedup vs baseline: 1.2426x; 1.2426x over previous
//
#include <hip/hip_runtime.h>
#include <stdint.h>
#include <math.h>

#define D_DIM 512
#define H_DIM 256
#define E_NUM 10
#define ROWS_PB 128          // rows per block (256 threads, 2 threads/row)
#define NSTEP 16             // steps; each stages 32 d-cols for all 128 rows

// ---------- precompute: packed weights pk[d/4][e][gate4|sim4] + bias_g ----------
__global__ __launch_bounds__(256) void pre_wg(const float* __restrict__ Wp,
                                              const float* __restrict__ bp,
                                              const float* __restrict__ emb,
                                              float* __restrict__ pk,
                                              float* __restrict__ bg) {
  int gid = blockIdx.x * 256 + threadIdx.x;
  if (gid < E_NUM * D_DIM) {
    int d = gid / E_NUM;
    int e = gid - d * E_NUM;
    const float* wr = Wp + (size_t)d * H_DIM;
    const float* er = emb + (size_t)e * H_DIM;
    float s0 = 0.f, s1 = 0.f, s2 = 0.f, s3 = 0.f;
#pragma unroll 4
    for (int h = 0; h < H_DIM; h += 4) {
      float4 a = *(const float4*)(wr + h);
      float4 b = *(const float4*)(er + h);
      s0 = fmaf(a.x, b.x, s0); s1 = fmaf(a.y, b.y, s1);
      s2 = fmaf(a.z, b.z, s2); s3 = fmaf(a.w, b.w, s3);
    }
    pk[(size_t)(d >> 2) * 80 + e * 8 + (d & 3)] = ((s0 + s1) + (s2 + s3)) * 0.0625f;
  } else if (gid < E_NUM * D_DIM + E_NUM) {
    int e = gid - E_NUM * D_DIM;
    const float* er = emb + (size_t)e * H_DIM;
    float s = 0.f;
    for (int h = 0; h < H_DIM; ++h) s = fmaf(bp[h], er[h], s);
    bg[e] = s * 0.0625f;
  }
}

// ---------- precompute: normalized expert rows into pk sim slots + trust*stale ----------
__global__ __launch_bounds__(64) void pre_en(const float* __restrict__ ef,
                                             const float* __restrict__ trust,
                                             const float* __restrict__ dtv,
                                             float* __restrict__ pk,
                                             float* __restrict__ cf) {
  int e = blockIdx.x, l = threadIdx.x;
  const float* row = ef + (size_t)e * D_DIM;
  float s = 0.f;
#pragma unroll
  for (int j = 0; j < D_DIM / 64; ++j) { float v = row[l + 64 * j]; s = fmaf(v, v, s); }
#pragma unroll
  for (int o = 32; o; o >>= 1) s += __shfl_xor(s, o, 64);
  float inv = 1.f / fmaxf(sqrtf(s), 1e-8f);
#pragma unroll
  for (int j = 0; j < D_DIM / 64; ++j) {
    int d = l + 64 * j;
    pk[(size_t)(d >> 2) * 80 + e * 8 + 4 + (d & 3)] = row[d] * inv;
  }
  if (l == 0) cf[e] = trust[e] * expf(-0.001f * dtv[e]);
}

// ---------- main: 2 threads per row (D split by wave-pair), gload_lds staging ----------
__global__ __launch_bounds__(256, 4) void router_main(
    const float* __restrict__ feat, const float* __restrict__ pk,
    const float* __restrict__ cf, const float* __restrict__ bg,
    float* __restrict__ out, int B) {
  __shared__ float lds[2][ROWS_PB * 32];
  const int t = threadIdx.x;
  const int l = t & 63;
  const int w = __builtin_amdgcn_readfirstlane(t >> 6);  // wave id 0..3 (SGPR)
  const int h = __builtin_amdgcn_readfirstlane(t >> 7);  // D-half  0..1 (SGPR)
  const int p = t & 127;                                 // row within block
  const size_t r0 = (size_t)blockIdx.x * ROWS_PB;

  // staging geometry: wave w stages rows w*8+(l>>3) (+32j); lane's global quad is
  // XOR-swizzled so the LINEAR gload_lds dest realizes the swizzled LDS layout.
  const int sr = w * 8 + (l >> 3);
  const int qg = (l & 7) ^ (l >> 3);
  const float* gbase = feat + (r0 + sr) * (size_t)D_DIM + ((qg >> 2) * 256 + (qg & 3) * 4);
  const int ldsbase = (w * 8) * 32;

  float gacc[E_NUM], sacc[E_NUM], nrm = 0.f;
#pragma unroll
  for (int e = 0; e < E_NUM; ++e) { gacc[e] = 0.f; sacc[e] = 0.f; }

  auto STAGE = [&](int buf, int c) {
#pragma unroll
    for (int j = 0; j < 4; ++j) {
      __builtin_amdgcn_global_load_lds(
          (const __attribute__((address_space(1))) uint32_t*)(gbase + (size_t)j * 32 * D_DIM + c * 16),
          (__attribute__((address_space(3))) uint32_t*)&lds[buf][ldsbase + j * 1024],
          16, 0, 0);
    }
  };

  auto COMPUTE = [&](int buf, int c) {
    const float* wb = pk + (size_t)(h * 64 + c * 4) * 80;  // wave-uniform -> s_load
#pragma unroll
    for (int q = 0; q < 4; ++q) {
      const int slot = ((h << 2) + q) ^ (p & 7);
      float4 fv = *(const float4*)&lds[buf][p * 32 + slot * 4];
      const float* qb = wb + q * 80;
#pragma unroll
      for (int e = 0; e < E_NUM; ++e) {
        float4 wv = *(const float4*)(qb + e * 8);
        float4 sv = *(const float4*)(qb + e * 8 + 4);
        float a = gacc[e];
        a = fmaf(fv.x, wv.x, a); a = fmaf(fv.y, wv.y, a);
        a = fmaf(fv.z, wv.z, a); a = fmaf(fv.w, wv.w, a);
        gacc[e] = a;
        float b2 = sacc[e];
        b2 = fmaf(fv.x, sv.x, b2); b2 = fmaf(fv.y, sv.y, b2);
        b2 = fmaf(fv.z, sv.z, b2); b2 = fmaf(fv.w, sv.w, b2);
        sacc[e] = b2;
      }
      nrm = fmaf(fv.x, fv.x, nrm); nrm = fmaf(fv.y, fv.y, nrm);
      nrm = fmaf(fv.z, fv.z, nrm); nrm = fmaf(fv.w, fv.w, nrm);
    }
  };

  STAGE(0, 0);
  asm volatile("s_waitcnt vmcnt(0)" ::: "memory");
  __syncthreads();
#pragma unroll 1
  for (int c = 0; c < NSTEP; ++c) {
    if (c + 1 < NSTEP) STAGE((c + 1) & 1, c + 1);
    COMPUTE(c & 1, c);
    asm volatile("s_waitcnt vmcnt(0)" ::: "memory");
    __syncthreads();
  }

  // ---------- cross-half reduction (reuse LDS) ----------
  if (h) {
    float* rp = &lds[0][p * 24];
#pragma unroll
    for (int e = 0; e < E_NUM; ++e) { rp[e] = gacc[e]; rp[E_NUM + e] = sacc[e]; }
    rp[2 * E_NUM] = nrm;
  }
  __syncthreads();
  if (h == 0) {
    const float* rp = &lds[0][p * 24];
#pragma unroll
    for (int e = 0; e < E_NUM; ++e) { gacc[e] += rp[e]; sacc[e] += rp[E_NUM + e]; }
    nrm += rp[2 * E_NUM];

    const float inv = 1.f / fmaxf(sqrtf(nrm), 1e-8f);
    float probs[E_NUM];
    float m = -1e30f;
#pragma unroll
    for (int e = 0; e < E_NUM; ++e) {
      float logit = gacc[e] + bg[e];
      float gate = 1.f / (1.f + __expf(-logit));
      float sim = fmaf(sacc[e] * inv, 0.5f, 0.5f);
      float sc = gate * cf[e] * sim;
      probs[e] = sc;
      m = fmaxf(m, sc);
    }
    float Z = 0.f;
#pragma unroll
    for (int e = 0; e < E_NUM; ++e) { float pe = __expf(probs[e] - m); probs[e] = pe; Z += pe; }
    const float invZ = 1.f / Z;
#pragma unroll
    for (int e = 0; e < E_NUM; ++e) probs[e] *= invZ;

    // stable top-3 (strict >, lowest index wins ties) == jax.lax.top_k
    int i0 = 0; float b0 = probs[0];
#pragma unroll
    for (int e = 1; e < E_NUM; ++e) if (probs[e] > b0) { b0 = probs[e]; i0 = e; }
    int i1 = -1; float b1 = -1.f;
#pragma unroll
    for (int e = 0; e < E_NUM; ++e) if (e != i0 && probs[e] > b1) { b1 = probs[e]; i1 = e; }
    int i2 = -1; float b2 = -1.f;
#pragma unroll
    for (int e = 0; e < E_NUM; ++e) if (e != i0 && e != i1 && probs[e] > b2) { b2 = probs[e]; i2 = e; }

    const float wnorm = 1.f / (b0 + b1 + b2);
    const size_t r = r0 + p;
    float* ow = out + r * 3;
    ow[0] = b0 * wnorm; ow[1] = b1 * wnorm; ow[2] = b2 * wnorm;
    float* oi = out + (size_t)B * 3 + r * 3;
    oi[0] = (float)i0; oi[1] = (float)i1; oi[2] = (float)i2;
    float* op = out + (size_t)B * 6 + r * E_NUM;
#pragma unroll
    for (int e = 0; e < E_NUM; ++e) op[e] = probs[e];
  }
}

extern "C" void kernel_launch(void* const* d_in, const int* in_sizes, int n_in,
                              void* d_out, int out_size, void* d_ws, size_t ws_size,
                              hipStream_t stream) {
  const float* feat  = (const float*)d_in[0];
  const float* Wp    = (const float*)d_in[1];
  const float* bp    = (const float*)d_in[2];
  const float* emb   = (const float*)d_in[3];
  const float* ef    = (const float*)d_in[4];
  const float* trust = (const float*)d_in[5];
  const float* dtv   = (const float*)d_in[6];
  float* out = (float*)d_out;

  float* pk = (float*)d_ws;                    // 128*80 = 10240 floats
  float* cf = pk + 128 * 80;                   // E_NUM
  float* bg = cf + E_NUM;                      // E_NUM

  const int B = in_sizes[0] / D_DIM;

  hipLaunchKernelGGL(pre_wg, dim3((E_NUM * D_DIM + E_NUM + 255) / 256), dim3(256),
                     0, stream, Wp, bp, emb, pk, bg);
  hipLaunchKernelGGL(pre_en, dim3(E_NUM), dim3(64), 0, stream, ef, trust, dtv, pk, cf);
  hipLaunchKernelGGL(router_main, dim3(B / ROWS_PB), dim3(256), 0, stream,
                     feat, pk, cf, bg, out, B);
}